// Round 6
// baseline (153.904 us; speedup 1.0000x reference)
//
#include <hip/hip_runtime.h>
#include <hip/hip_bf16.h>
#include <math.h>

#define N_NODES 20000
#define N_EDGES 200000
#define D_H 32
#define E_DIM 16
#define NTILES (N_EDGES / 16)           // 12500
#define NJOBS (NTILES / 2)              // 6250 (2 tiles per wave-job)
#define W2S_SHORTS (17 * 2 * 64 * 8)    // 17408 bf16: 17 K-steps x 2 col-tiles x 64 lanes x 8
#define PREP_SHORTS (W2S_SHORTS + 512)  // + w1/b1 A-fragment = 17920

typedef __attribute__((ext_vector_type(8))) short bf16x8;
typedef __attribute__((ext_vector_type(4))) float f32x4;

__device__ __forceinline__ float elu_f(float v) { return v > 0.f ? v : expm1f(v); }
__device__ __forceinline__ short f2bf(float f) {
    union { __hip_bfloat16 h; short s; } u;
    u.h = __float2bfloat16(f);
    return u.s;
}
__device__ __forceinline__ float bf2f(__hip_bfloat16 h) { return __bfloat162float(h); }

// ---------------- init: zero cnt + build bf16 weight fragments (both layers) ----------------
// W2 A-frags: buf[((kk*2+ct)*64+l)*8+j] = A[o = ct*16 + (l&15)][i = (l>>4)*8+j] of K-step kk
//   = w2[kk][i*32+o] (kk<16) or b2[i*32+o] (kk==16)
// w1 A-frag (for swapped h-MFMA, D = h^T): buf[W2S + l*8+j] = A[m=l&15][k=(l>>4)*8+j]
//   = w1[k][m] (k<16), b1[m] (k==16), 0 else
__global__ __launch_bounds__(256)
void init_kernel(const float* __restrict__ w2_0, const float* __restrict__ b2_0,
                 const float* __restrict__ w1_0, const float* __restrict__ b1_0,
                 const float* __restrict__ w2_1, const float* __restrict__ b2_1,
                 const float* __restrict__ w1_1, const float* __restrict__ b1_1,
                 int* __restrict__ cnt, short* __restrict__ prep)
{
    const int gid = blockIdx.x * 256 + threadIdx.x;
    if (gid < N_NODES) cnt[gid] = 0;
    if (gid < 2 * PREP_SHORTS) {
        int layer = gid >= PREP_SHORTS ? 1 : 0;
        int r = gid - layer * PREP_SHORTS;
        const float* w2 = layer ? w2_1 : w2_0;
        const float* b2 = layer ? b2_1 : b2_0;
        const float* w1 = layer ? w1_1 : w1_0;
        const float* b1 = layer ? b1_1 : b1_0;
        float v;
        if (r < W2S_SHORTS) {
            int j = r & 7, l = (r >> 3) & 63, ct = (r >> 9) & 1, kk = r >> 10;
            int ii = (l >> 4) * 8 + j;
            int o = ct * 16 + (l & 15);
            v = (kk < 16) ? w2[kk * 1024 + ii * 32 + o] : b2[ii * 32 + o];
        } else {
            int q = r - W2S_SHORTS;
            int j = q & 7, l = q >> 3;
            int m = l & 15, k = (l >> 4) * 8 + j;
            v = (k < 16) ? w1[k * 16 + m] : (k == 16 ? b1[m] : 0.f);
        }
        prep[gid] = f2bf(v);
    }
}

// ---------------- histogram + arrival rank (merged deg+fill) ----------------
__global__ __launch_bounds__(256)
void hist_kernel(const int* __restrict__ dst, int* __restrict__ cnt, int* __restrict__ ord) {
    int e = blockIdx.x * 256 + threadIdx.x;
    if (e < N_EDGES) ord[e] = atomicAdd(&cnt[dst[e]], 1);
}

// ---------------- exclusive scan of counts -> rowptr, single block ----------------
__global__ __launch_bounds__(1024)
void scan_kernel(const int* __restrict__ cnt, int* __restrict__ rowptr) {
    __shared__ int part[1024];
    const int t = threadIdx.x;
    const int base = t * 20;
    int loc[20];
    int sum = 0;
    #pragma unroll
    for (int j = 0; j < 20; ++j) {
        int idx = base + j;
        int v = (idx < N_NODES) ? cnt[idx] : 0;
        loc[j] = v;
        sum += v;
    }
    part[t] = sum;
    __syncthreads();
    for (int off = 1; off < 1024; off <<= 1) {
        int v = (t >= off) ? part[t - off] : 0;
        __syncthreads();
        part[t] += v;
        __syncthreads();
    }
    int run = part[t] - sum;
    #pragma unroll
    for (int j = 0; j < 20; ++j) {
        int idx = base + j;
        if (idx < N_NODES) { rowptr[idx] = run; run += loc[j]; }
    }
    if (t == 0) rowptr[N_NODES] = N_EDGES;
}

// ---------------- fused edge kernel: 2 tiles (32 edges) per wave ----------------
// h^T via swapped MFMA + 16 shfl (no LDS round-trip); msg-GEMM shares each
// A-fragment ds_read across both tiles' MFMAs (halves LDS read traffic).
__global__ __launch_bounds__(512, 4)
void edge_kernel(const float* __restrict__ xin,
                 const float* __restrict__ edge_attr,
                 const int* __restrict__ src,
                 const int* __restrict__ dst,
                 const int* __restrict__ ord,
                 const int* __restrict__ rowptr,
                 const short* __restrict__ prepL,
                 __hip_bfloat16* __restrict__ msg)
{
    __shared__ __align__(16) short w2s[PREP_SHORTS];   // 35840 B

    const int t = threadIdx.x;
    for (int i = t; i < PREP_SHORTS / 8; i += 512)
        ((int4*)w2s)[i] = ((const int4*)prepL)[i];
    __syncthreads();

    const int lane = t & 63;
    const int wave = t >> 6;
    const int job = blockIdx.x * 8 + wave;
    if (job >= NJOBS) return;
    const int eloc = lane & 15;
    const int kg = lane >> 4;

    const int e0 = job * 32 + eloc;
    const int e1 = e0 + 16;

    // issue index gathers early
    const int sn0 = src[e0], sn1 = src[e1];
    const int pe0 = rowptr[dst[e0]] + ord[e0];
    const int pe1 = rowptr[dst[e1]] + ord[e1];

    const float4 xa0 = *(const float4*)(xin + (size_t)sn0 * 32 + kg * 8);
    const float4 xa1 = *(const float4*)(xin + (size_t)sn0 * 32 + kg * 8 + 4);
    const float4 xb0_ = *(const float4*)(xin + (size_t)sn1 * 32 + kg * 8);
    const float4 xb1_ = *(const float4*)(xin + (size_t)sn1 * 32 + kg * 8 + 4);

    // edge-attr B-frags: B[k=kg*8+j][n=eloc]; k==16 -> 1.0 (bias), else 0
    bf16x8 ea0 = {0,0,0,0,0,0,0,0}, ea1 = {0,0,0,0,0,0,0,0};
    if (kg < 2) {
        const float4 p0 = *(const float4*)(edge_attr + (size_t)e0 * E_DIM + kg * 8);
        const float4 p1 = *(const float4*)(edge_attr + (size_t)e0 * E_DIM + kg * 8 + 4);
        ea0[0]=f2bf(p0.x); ea0[1]=f2bf(p0.y); ea0[2]=f2bf(p0.z); ea0[3]=f2bf(p0.w);
        ea0[4]=f2bf(p1.x); ea0[5]=f2bf(p1.y); ea0[6]=f2bf(p1.z); ea0[7]=f2bf(p1.w);
        const float4 q0 = *(const float4*)(edge_attr + (size_t)e1 * E_DIM + kg * 8);
        const float4 q1 = *(const float4*)(edge_attr + (size_t)e1 * E_DIM + kg * 8 + 4);
        ea1[0]=f2bf(q0.x); ea1[1]=f2bf(q0.y); ea1[2]=f2bf(q0.z); ea1[3]=f2bf(q0.w);
        ea1[4]=f2bf(q1.x); ea1[5]=f2bf(q1.y); ea1[6]=f2bf(q1.z); ea1[7]=f2bf(q1.w);
    } else if (kg == 2) {
        ea0[0] = f2bf(1.0f);
        ea1[0] = f2bf(1.0f);
    }

    const f32x4 zero4 = {0.f, 0.f, 0.f, 0.f};

    // h-MFMA (swapped): D[k_out=kg*4+r][edge=eloc]; elu then redistribute via shfl
    bf16x8 w1f = *(const bf16x8*)&w2s[W2S_SHORTS + lane * 8];
    f32x4 hd0 = __builtin_amdgcn_mfma_f32_16x16x32_bf16(w1f, ea0, zero4, 0, 0, 0);
    f32x4 hd1 = __builtin_amdgcn_mfma_f32_16x16x32_bf16(w1f, ea1, zero4, 0, 0, 0);
    float hv0[4], hv1[4];
    #pragma unroll
    for (int r = 0; r < 4; ++r) { hv0[r] = elu_f(hd0[r]); hv1[r] = elu_f(hd1[r]); }

    float hr0[17], hr1[17];
    #pragma unroll
    for (int kq = 0; kq < 4; ++kq)
        #pragma unroll
        for (int r = 0; r < 4; ++r) {
            hr0[kq * 4 + r] = __shfl(hv0[r], kq * 16 + eloc);
            hr1[kq * 4 + r] = __shfl(hv1[r], kq * 16 + eloc);
        }
    hr0[16] = 1.0f; hr1[16] = 1.0f;   // b2 K-step

    // x B-frags: B[k=kg*8+j][n=eloc] = x[e][kg*8+j]
    bf16x8 xf0, xf1;
    xf0[0]=f2bf(xa0.x); xf0[1]=f2bf(xa0.y); xf0[2]=f2bf(xa0.z); xf0[3]=f2bf(xa0.w);
    xf0[4]=f2bf(xa1.x); xf0[5]=f2bf(xa1.y); xf0[6]=f2bf(xa1.z); xf0[7]=f2bf(xa1.w);
    xf1[0]=f2bf(xb0_.x); xf1[1]=f2bf(xb0_.y); xf1[2]=f2bf(xb0_.z); xf1[3]=f2bf(xb0_.w);
    xf1[4]=f2bf(xb1_.x); xf1[5]=f2bf(xb1_.y); xf1[6]=f2bf(xb1_.z); xf1[7]=f2bf(xb1_.w);

    float m00[4]={0,0,0,0}, m01[4]={0,0,0,0}, m10[4]={0,0,0,0}, m11[4]={0,0,0,0};
    #pragma unroll
    for (int kk = 0; kk < 17; ++kk) {
        bf16x8 a0 = *(const bf16x8*)&w2s[(kk * 2 + 0) * 512 + lane * 8];
        bf16x8 a1 = *(const bf16x8*)&w2s[(kk * 2 + 1) * 512 + lane * 8];
        f32x4 d00 = __builtin_amdgcn_mfma_f32_16x16x32_bf16(a0, xf0, zero4, 0, 0, 0);
        f32x4 d01 = __builtin_amdgcn_mfma_f32_16x16x32_bf16(a1, xf0, zero4, 0, 0, 0);
        f32x4 d10 = __builtin_amdgcn_mfma_f32_16x16x32_bf16(a0, xf1, zero4, 0, 0, 0);
        f32x4 d11 = __builtin_amdgcn_mfma_f32_16x16x32_bf16(a1, xf1, zero4, 0, 0, 0);
        const float h0 = hr0[kk], h1 = hr1[kk];
        #pragma unroll
        for (int r = 0; r < 4; ++r) {
            m00[r] += h0 * d00[r]; m01[r] += h0 * d01[r];
            m10[r] += h1 * d10[r]; m11[r] += h1 * d11[r];
        }
    }

    // CSR-ordered stores: lane owns msg[pe][kg*4..+3] and msg[pe][16+kg*4..+3]
    short* mp0 = (short*)(msg + (size_t)pe0 * D_H);
    short* mp1 = (short*)(msg + (size_t)pe1 * D_H);
    short q00[4] = { f2bf(m00[0]), f2bf(m00[1]), f2bf(m00[2]), f2bf(m00[3]) };
    short q01[4] = { f2bf(m01[0]), f2bf(m01[1]), f2bf(m01[2]), f2bf(m01[3]) };
    short q10[4] = { f2bf(m10[0]), f2bf(m10[1]), f2bf(m10[2]), f2bf(m10[3]) };
    short q11[4] = { f2bf(m11[0]), f2bf(m11[1]), f2bf(m11[2]), f2bf(m11[3]) };
    *(int2*)(mp0 + kg * 4)      = *(int2*)q00;
    *(int2*)(mp0 + 16 + kg * 4) = *(int2*)q01;
    *(int2*)(mp1 + kg * 4)      = *(int2*)q10;
    *(int2*)(mp1 + 16 + kg * 4) = *(int2*)q11;
}

// ---------------- aggregation: wave per node, contiguous rows, 4-deep prefetch ----------------
template<bool LAST>
__global__ __launch_bounds__(256)
void agg_kernel(const float* __restrict__ xin,
                const __hip_bfloat16* __restrict__ msg,   // CSR-ordered rows
                const int* __restrict__ rowptr,
                const float* __restrict__ root,
                const float* __restrict__ bias,
                const float* __restrict__ cls_w,
                const float* __restrict__ cls_b,
                float* __restrict__ hout,
                float* __restrict__ out)
{
    __shared__ float root_s[32 * 32];
    __shared__ float bias_s[32];
    __shared__ float h2_s[4][33];
    const int t = threadIdx.x;
    for (int i = t; i < 1024; i += 256) root_s[i] = root[i];
    if (t < 32) bias_s[t] = bias[t];
    __syncthreads();

    const int lane = t & 63;
    const int wave = t >> 6;
    const int o = lane & 31;
    const int half = lane >> 5;
    const int n = blockIdx.x * 4 + wave;

    const int start = rowptr[n];
    const int end   = rowptr[n + 1];
    float s = 0.f;
    int j = start + half;
    for (; j + 6 < end; j += 8) {   // 4 independent row-loads in flight per half
        float v0 = bf2f(msg[(size_t)(j    ) * D_H + o]);
        float v1 = bf2f(msg[(size_t)(j + 2) * D_H + o]);
        float v2 = bf2f(msg[(size_t)(j + 4) * D_H + o]);
        float v3 = bf2f(msg[(size_t)(j + 6) * D_H + o]);
        s += (v0 + v1) + (v2 + v3);
    }
    for (; j < end; j += 2)
        s += bf2f(msg[(size_t)j * D_H + o]);
    s += __shfl_xor(s, 32);

    float acc = s * (1.f / fmaxf((float)(end - start), 1.f)) + bias_s[o];
    const float xv = xin[(size_t)n * 32 + o];
    #pragma unroll
    for (int i = 0; i < 32; ++i)
        acc += __shfl(xv, half * 32 + i) * root_s[i * 32 + o];
    acc = elu_f(acc);

    if (!LAST) {
        if (half == 0) hout[(size_t)n * 32 + o] = acc;
    } else {
        if (half == 0) h2_s[wave][o] = acc;
        __syncthreads();
        if (t < 32) {
            const int nn = t >> 3, jj = t & 7;
            float a = cls_b[jj];
            #pragma unroll
            for (int i = 0; i < 32; ++i) a += h2_s[nn][i] * cls_w[i * 8 + jj];
            out[(size_t)(blockIdx.x * 4 + nn) * 8 + jj] = a;
        }
    }
}

extern "C" void kernel_launch(void* const* d_in, const int* in_sizes, int n_in,
                              void* d_out, int out_size, void* d_ws, size_t ws_size,
                              hipStream_t stream)
{
    const float* x          = (const float*)d_in[0];
    const float* edge_attr  = (const float*)d_in[1];
    const int*   edge_index = (const int*)d_in[2];
    const float* w1_0 = (const float*)d_in[3];
    const float* b1_0 = (const float*)d_in[4];
    const float* w2_0 = (const float*)d_in[5];
    const float* b2_0 = (const float*)d_in[6];
    const float* root_0 = (const float*)d_in[7];
    const float* bias_0 = (const float*)d_in[8];
    const float* w1_1 = (const float*)d_in[9];
    const float* b1_1 = (const float*)d_in[10];
    const float* w2_1 = (const float*)d_in[11];
    const float* b2_1 = (const float*)d_in[12];
    const float* root_1 = (const float*)d_in[13];
    const float* bias_1 = (const float*)d_in[14];
    const float* cls_w = (const float*)d_in[15];
    const float* cls_b = (const float*)d_in[16];

    const int* src = edge_index;
    const int* dst = edge_index + N_EDGES;

    char* ws = (char*)d_ws;
    int* cnt    = (int*)ws;                            // 20000
    int* rowptr = cnt + N_NODES;                       // 20001
    int* ord    = rowptr + N_NODES + 1;                // 200000
    size_t off = ((size_t)(2 * N_NODES + 1 + N_EDGES) * 4 + 15) & ~(size_t)15;
    short* prep = (short*)(ws + off);                  // 2 x 17920 shorts
    off = (off + (size_t)2 * PREP_SHORTS * 2 + 15) & ~(size_t)15;
    __hip_bfloat16* msg = (__hip_bfloat16*)(ws + off); // E*32 bf16 = 12.8 MB
    off = (off + (size_t)N_EDGES * D_H * 2 + 15) & ~(size_t)15;
    float* hbuf = (float*)(ws + off);                  // N*32 f32

    const int EB = (N_EDGES + 255) / 256;         // 782
    const int IB = (2 * PREP_SHORTS + 255) / 256; // 140 (covers N_NODES too)
    const int GB = (NJOBS + 7) / 8;               // 782

    init_kernel<<<IB, 256, 0, stream>>>(w2_0, b2_0, w1_0, b1_0,
                                        w2_1, b2_1, w1_1, b1_1, cnt, prep);
    hist_kernel<<<EB, 256, 0, stream>>>(dst, cnt, ord);
    scan_kernel<<<1, 1024, 0, stream>>>(cnt, rowptr);

    // layer 0
    edge_kernel<<<GB, 512, 0, stream>>>(x, edge_attr, src, dst, ord, rowptr, prep, msg);
    agg_kernel<false><<<N_NODES / 4, 256, 0, stream>>>(x, msg, rowptr, root_0, bias_0,
                                                       nullptr, nullptr, hbuf, nullptr);
    // layer 1 (+ fused classifier)
    edge_kernel<<<GB, 512, 0, stream>>>(hbuf, edge_attr, src, dst, ord, rowptr,
                                        prep + PREP_SHORTS, msg);
    agg_kernel<true><<<N_NODES / 4, 256, 0, stream>>>(hbuf, msg, rowptr, root_1, bias_1,
                                                      cls_w, cls_b, nullptr, (float*)d_out);
}

// Round 7
// 114.841 us; speedup vs baseline: 1.3401x; 1.3401x over previous
//
#include <hip/hip_runtime.h>
#include <hip/hip_bf16.h>
#include <math.h>

#define N_NODES 20000
#define N_EDGES 200000
#define D_H 32
#define E_DIM 16
#define NTILES (N_EDGES / 16)           // 12500
#define NJOBS (NTILES / 2)              // 6250 (2 tiles per wave-job)
#define W2S_SHORTS (17 * 2 * 64 * 8)    // 17408 bf16: 17 K-steps x 2 col-tiles x 64 lanes x 8
#define PREP_SHORTS (W2S_SHORTS + 512)  // + w1/b1 A-fragment = 17920

typedef __attribute__((ext_vector_type(8))) short bf16x8;
typedef __attribute__((ext_vector_type(4))) float f32x4;

__device__ __forceinline__ float elu_f(float v) { return v > 0.f ? v : expm1f(v); }
__device__ __forceinline__ short f2bf(float f) {
    union { __hip_bfloat16 h; short s; } u;
    u.h = __float2bfloat16(f);
    return u.s;
}
__device__ __forceinline__ float bf2f(__hip_bfloat16 h) { return __bfloat162float(h); }

// ---------------- init: zero cnt + build bf16 weight fragments (both layers) ----------------
__global__ __launch_bounds__(256)
void init_kernel(const float* __restrict__ w2_0, const float* __restrict__ b2_0,
                 const float* __restrict__ w1_0, const float* __restrict__ b1_0,
                 const float* __restrict__ w2_1, const float* __restrict__ b2_1,
                 const float* __restrict__ w1_1, const float* __restrict__ b1_1,
                 int* __restrict__ cnt, short* __restrict__ prep)
{
    const int gid = blockIdx.x * 256 + threadIdx.x;
    if (gid < N_NODES) cnt[gid] = 0;
    if (gid < 2 * PREP_SHORTS) {
        int layer = gid >= PREP_SHORTS ? 1 : 0;
        int r = gid - layer * PREP_SHORTS;
        const float* w2 = layer ? w2_1 : w2_0;
        const float* b2 = layer ? b2_1 : b2_0;
        const float* w1 = layer ? w1_1 : w1_0;
        const float* b1 = layer ? b1_1 : b1_0;
        float v;
        if (r < W2S_SHORTS) {
            int j = r & 7, l = (r >> 3) & 63, ct = (r >> 9) & 1, kk = r >> 10;
            int ii = (l >> 4) * 8 + j;
            int o = ct * 16 + (l & 15);
            v = (kk < 16) ? w2[kk * 1024 + ii * 32 + o] : b2[ii * 32 + o];
        } else {
            int q = r - W2S_SHORTS;
            int j = q & 7, l = q >> 3;
            int m = l & 15, k = (l >> 4) * 8 + j;
            v = (k < 16) ? w1[k * 16 + m] : (k == 16 ? b1[m] : 0.f);
        }
        prep[gid] = f2bf(v);
    }
}

// ---------------- histogram + arrival rank ----------------
__global__ __launch_bounds__(256)
void hist_kernel(const int* __restrict__ dst, int* __restrict__ cnt, int* __restrict__ ord) {
    int e = blockIdx.x * 256 + threadIdx.x;
    if (e < N_EDGES) ord[e] = atomicAdd(&cnt[dst[e]], 1);
}

// ---------------- exclusive scan of counts -> rowptr, single block ----------------
__global__ __launch_bounds__(1024)
void scan_kernel(const int* __restrict__ cnt, int* __restrict__ rowptr) {
    __shared__ int part[1024];
    const int t = threadIdx.x;
    const int base = t * 20;
    int loc[20];
    int sum = 0;
    #pragma unroll
    for (int j = 0; j < 20; ++j) {
        int idx = base + j;
        int v = (idx < N_NODES) ? cnt[idx] : 0;
        loc[j] = v;
        sum += v;
    }
    part[t] = sum;
    __syncthreads();
    for (int off = 1; off < 1024; off <<= 1) {
        int v = (t >= off) ? part[t - off] : 0;
        __syncthreads();
        part[t] += v;
        __syncthreads();
    }
    int run = part[t] - sum;
    #pragma unroll
    for (int j = 0; j < 20; ++j) {
        int idx = base + j;
        if (idx < N_NODES) { rowptr[idx] = run; run += loc[j]; }
    }
    if (t == 0) rowptr[N_NODES] = N_EDGES;
}

// ---------------- fused edge kernel: 2 tiles (32 edges) per wave ----------------
// No min-waves bound (R6's (512,4) caused 64-VGPR cap -> scratch spills, WRITE 90MB).
// h redistribution via inline shfl in the unrolled kk loop (no hr[17] arrays).
template<bool BF16IN>
__global__ __launch_bounds__(512)
void edge_kernel(const void* __restrict__ xin_,
                 const float* __restrict__ edge_attr,
                 const int* __restrict__ src,
                 const int* __restrict__ dst,
                 const int* __restrict__ ord,
                 const int* __restrict__ rowptr,
                 const short* __restrict__ prepL,
                 __hip_bfloat16* __restrict__ msg)
{
    __shared__ __align__(16) short w2s[PREP_SHORTS];   // 35840 B

    const int t = threadIdx.x;
    for (int i = t; i < PREP_SHORTS / 8; i += 512)
        ((int4*)w2s)[i] = ((const int4*)prepL)[i];
    __syncthreads();

    const int lane = t & 63;
    const int wave = t >> 6;
    const int job = blockIdx.x * 8 + wave;
    if (job >= NJOBS) return;
    const int eloc = lane & 15;
    const int kg = lane >> 4;

    const int e0 = job * 32 + eloc;
    const int e1 = e0 + 16;

    // issue index gathers early
    const int sn0 = src[e0], sn1 = src[e1];
    const int pe0 = rowptr[dst[e0]] + ord[e0];
    const int pe1 = rowptr[dst[e1]] + ord[e1];

    // x B-frags: B[k=kg*8+j][n=eloc] = x[e][kg*8+j]
    bf16x8 xf0, xf1;
    if (BF16IN) {
        const short* xb = (const short*)xin_;
        xf0 = *(const bf16x8*)(xb + (size_t)sn0 * 32 + kg * 8);
        xf1 = *(const bf16x8*)(xb + (size_t)sn1 * 32 + kg * 8);
    } else {
        const float* xf = (const float*)xin_;
        const float4 xa0 = *(const float4*)(xf + (size_t)sn0 * 32 + kg * 8);
        const float4 xa1 = *(const float4*)(xf + (size_t)sn0 * 32 + kg * 8 + 4);
        const float4 xb0 = *(const float4*)(xf + (size_t)sn1 * 32 + kg * 8);
        const float4 xb1 = *(const float4*)(xf + (size_t)sn1 * 32 + kg * 8 + 4);
        xf0[0]=f2bf(xa0.x); xf0[1]=f2bf(xa0.y); xf0[2]=f2bf(xa0.z); xf0[3]=f2bf(xa0.w);
        xf0[4]=f2bf(xa1.x); xf0[5]=f2bf(xa1.y); xf0[6]=f2bf(xa1.z); xf0[7]=f2bf(xa1.w);
        xf1[0]=f2bf(xb0.x); xf1[1]=f2bf(xb0.y); xf1[2]=f2bf(xb0.z); xf1[3]=f2bf(xb0.w);
        xf1[4]=f2bf(xb1.x); xf1[5]=f2bf(xb1.y); xf1[6]=f2bf(xb1.z); xf1[7]=f2bf(xb1.w);
    }

    // edge-attr B-frags: B[k=kg*8+j][n=eloc]; k==16 -> 1.0 (bias), else 0
    bf16x8 ea0 = {0,0,0,0,0,0,0,0}, ea1 = {0,0,0,0,0,0,0,0};
    if (kg < 2) {
        const float4 p0 = *(const float4*)(edge_attr + (size_t)e0 * E_DIM + kg * 8);
        const float4 p1 = *(const float4*)(edge_attr + (size_t)e0 * E_DIM + kg * 8 + 4);
        ea0[0]=f2bf(p0.x); ea0[1]=f2bf(p0.y); ea0[2]=f2bf(p0.z); ea0[3]=f2bf(p0.w);
        ea0[4]=f2bf(p1.x); ea0[5]=f2bf(p1.y); ea0[6]=f2bf(p1.z); ea0[7]=f2bf(p1.w);
        const float4 q0 = *(const float4*)(edge_attr + (size_t)e1 * E_DIM + kg * 8);
        const float4 q1 = *(const float4*)(edge_attr + (size_t)e1 * E_DIM + kg * 8 + 4);
        ea1[0]=f2bf(q0.x); ea1[1]=f2bf(q0.y); ea1[2]=f2bf(q0.z); ea1[3]=f2bf(q0.w);
        ea1[4]=f2bf(q1.x); ea1[5]=f2bf(q1.y); ea1[6]=f2bf(q1.z); ea1[7]=f2bf(q1.w);
    } else if (kg == 2) {
        ea0[0] = f2bf(1.0f);
        ea1[0] = f2bf(1.0f);
    }

    const f32x4 zero4 = {0.f, 0.f, 0.f, 0.f};

    // h-MFMA (swapped): lane holds h[k_out=(lane>>4)*4+r][edge=lane&15]
    bf16x8 w1f = *(const bf16x8*)&w2s[W2S_SHORTS + lane * 8];
    f32x4 hd0 = __builtin_amdgcn_mfma_f32_16x16x32_bf16(w1f, ea0, zero4, 0, 0, 0);
    f32x4 hd1 = __builtin_amdgcn_mfma_f32_16x16x32_bf16(w1f, ea1, zero4, 0, 0, 0);
    float hv0[4], hv1[4];
    #pragma unroll
    for (int r = 0; r < 4; ++r) { hv0[r] = elu_f(hd0[r]); hv1[r] = elu_f(hd1[r]); }

    float m00[4]={0,0,0,0}, m01[4]={0,0,0,0}, m10[4]={0,0,0,0}, m11[4]={0,0,0,0};
    #pragma unroll
    for (int kk = 0; kk < 17; ++kk) {
        bf16x8 a0 = *(const bf16x8*)&w2s[(kk * 2 + 0) * 512 + lane * 8];
        bf16x8 a1 = *(const bf16x8*)&w2s[(kk * 2 + 1) * 512 + lane * 8];
        // h[kk][eloc] lives in lane (kk>>2)*16+eloc, reg kk&3 (static idx: loop unrolled)
        float h0, h1;
        if (kk < 16) {
            h0 = __shfl(hv0[kk & 3], (kk >> 2) * 16 + eloc);
            h1 = __shfl(hv1[kk & 3], (kk >> 2) * 16 + eloc);
        } else {
            h0 = 1.0f; h1 = 1.0f;   // b2 K-step
        }
        f32x4 d00 = __builtin_amdgcn_mfma_f32_16x16x32_bf16(a0, xf0, zero4, 0, 0, 0);
        f32x4 d01 = __builtin_amdgcn_mfma_f32_16x16x32_bf16(a1, xf0, zero4, 0, 0, 0);
        f32x4 d10 = __builtin_amdgcn_mfma_f32_16x16x32_bf16(a0, xf1, zero4, 0, 0, 0);
        f32x4 d11 = __builtin_amdgcn_mfma_f32_16x16x32_bf16(a1, xf1, zero4, 0, 0, 0);
        #pragma unroll
        for (int r = 0; r < 4; ++r) {
            m00[r] += h0 * d00[r]; m01[r] += h0 * d01[r];
            m10[r] += h1 * d10[r]; m11[r] += h1 * d11[r];
        }
    }

    // CSR-ordered stores: lane owns msg[pe][kg*4..+3] and msg[pe][16+kg*4..+3]
    short* mp0 = (short*)(msg + (size_t)pe0 * D_H);
    short* mp1 = (short*)(msg + (size_t)pe1 * D_H);
    short q00[4] = { f2bf(m00[0]), f2bf(m00[1]), f2bf(m00[2]), f2bf(m00[3]) };
    short q01[4] = { f2bf(m01[0]), f2bf(m01[1]), f2bf(m01[2]), f2bf(m01[3]) };
    short q10[4] = { f2bf(m10[0]), f2bf(m10[1]), f2bf(m10[2]), f2bf(m10[3]) };
    short q11[4] = { f2bf(m11[0]), f2bf(m11[1]), f2bf(m11[2]), f2bf(m11[3]) };
    *(int2*)(mp0 + kg * 4)      = *(int2*)q00;
    *(int2*)(mp0 + 16 + kg * 4) = *(int2*)q01;
    *(int2*)(mp1 + kg * 4)      = *(int2*)q10;
    *(int2*)(mp1 + 16 + kg * 4) = *(int2*)q11;
}

// ---------------- aggregation: wave per node, contiguous rows, 4-deep prefetch ----------------
// LAST=false: xin is f32, hout written as bf16. LAST=true: xin is bf16 (hbuf), classifier fused.
template<bool LAST>
__global__ __launch_bounds__(256)
void agg_kernel(const void* __restrict__ xin_,
                const __hip_bfloat16* __restrict__ msg,   // CSR-ordered rows
                const int* __restrict__ rowptr,
                const float* __restrict__ root,
                const float* __restrict__ bias,
                const float* __restrict__ cls_w,
                const float* __restrict__ cls_b,
                __hip_bfloat16* __restrict__ hout,
                float* __restrict__ out)
{
    __shared__ float root_s[32 * 32];
    __shared__ float bias_s[32];
    __shared__ float h2_s[4][33];
    const int t = threadIdx.x;
    for (int i = t; i < 1024; i += 256) root_s[i] = root[i];
    if (t < 32) bias_s[t] = bias[t];
    __syncthreads();

    const int lane = t & 63;
    const int wave = t >> 6;
    const int o = lane & 31;
    const int half = lane >> 5;
    const int n = blockIdx.x * 4 + wave;

    const int start = rowptr[n];
    const int end   = rowptr[n + 1];
    float s = 0.f;
    int j = start + half;
    for (; j + 6 < end; j += 8) {   // 4 independent row-loads in flight per half
        float v0 = bf2f(msg[(size_t)(j    ) * D_H + o]);
        float v1 = bf2f(msg[(size_t)(j + 2) * D_H + o]);
        float v2 = bf2f(msg[(size_t)(j + 4) * D_H + o]);
        float v3 = bf2f(msg[(size_t)(j + 6) * D_H + o]);
        s += (v0 + v1) + (v2 + v3);
    }
    for (; j < end; j += 2)
        s += bf2f(msg[(size_t)j * D_H + o]);
    s += __shfl_xor(s, 32);

    float acc = s * (1.f / fmaxf((float)(end - start), 1.f)) + bias_s[o];
    const float xv = LAST ? bf2f(((const __hip_bfloat16*)xin_)[(size_t)n * 32 + o])
                          : ((const float*)xin_)[(size_t)n * 32 + o];
    #pragma unroll
    for (int i = 0; i < 32; ++i)
        acc += __shfl(xv, half * 32 + i) * root_s[i * 32 + o];
    acc = elu_f(acc);

    if (!LAST) {
        if (half == 0) hout[(size_t)n * 32 + o] = __float2bfloat16(acc);
    } else {
        if (half == 0) h2_s[wave][o] = acc;
        __syncthreads();
        if (t < 32) {
            const int nn = t >> 3, jj = t & 7;
            float a = cls_b[jj];
            #pragma unroll
            for (int i = 0; i < 32; ++i) a += h2_s[nn][i] * cls_w[i * 8 + jj];
            out[(size_t)(blockIdx.x * 4 + nn) * 8 + jj] = a;
        }
    }
}

extern "C" void kernel_launch(void* const* d_in, const int* in_sizes, int n_in,
                              void* d_out, int out_size, void* d_ws, size_t ws_size,
                              hipStream_t stream)
{
    const float* x          = (const float*)d_in[0];
    const float* edge_attr  = (const float*)d_in[1];
    const int*   edge_index = (const int*)d_in[2];
    const float* w1_0 = (const float*)d_in[3];
    const float* b1_0 = (const float*)d_in[4];
    const float* w2_0 = (const float*)d_in[5];
    const float* b2_0 = (const float*)d_in[6];
    const float* root_0 = (const float*)d_in[7];
    const float* bias_0 = (const float*)d_in[8];
    const float* w1_1 = (const float*)d_in[9];
    const float* b1_1 = (const float*)d_in[10];
    const float* w2_1 = (const float*)d_in[11];
    const float* b2_1 = (const float*)d_in[12];
    const float* root_1 = (const float*)d_in[13];
    const float* bias_1 = (const float*)d_in[14];
    const float* cls_w = (const float*)d_in[15];
    const float* cls_b = (const float*)d_in[16];

    const int* src = edge_index;
    const int* dst = edge_index + N_EDGES;

    char* ws = (char*)d_ws;
    int* cnt    = (int*)ws;                            // 20000
    int* rowptr = cnt + N_NODES;                       // 20001
    int* ord    = rowptr + N_NODES + 1;                // 200000
    size_t off = ((size_t)(2 * N_NODES + 1 + N_EDGES) * 4 + 15) & ~(size_t)15;
    short* prep = (short*)(ws + off);                  // 2 x 17920 shorts
    off = (off + (size_t)2 * PREP_SHORTS * 2 + 15) & ~(size_t)15;
    __hip_bfloat16* msg = (__hip_bfloat16*)(ws + off); // E*32 bf16 = 12.8 MB
    off = (off + (size_t)N_EDGES * D_H * 2 + 15) & ~(size_t)15;
    __hip_bfloat16* hbuf = (__hip_bfloat16*)(ws + off); // N*32 bf16

    const int EB = (N_EDGES + 255) / 256;         // 782
    const int IB = (2 * PREP_SHORTS + 255) / 256; // 140 (covers N_NODES too)
    const int GB = (NJOBS + 7) / 8;               // 782

    init_kernel<<<IB, 256, 0, stream>>>(w2_0, b2_0, w1_0, b1_0,
                                        w2_1, b2_1, w1_1, b1_1, cnt, prep);
    hist_kernel<<<EB, 256, 0, stream>>>(dst, cnt, ord);
    scan_kernel<<<1, 1024, 0, stream>>>(cnt, rowptr);

    // layer 0 (f32 x in)
    edge_kernel<false><<<GB, 512, 0, stream>>>(x, edge_attr, src, dst, ord, rowptr,
                                               prep, msg);
    agg_kernel<false><<<N_NODES / 4, 256, 0, stream>>>(x, msg, rowptr, root_0, bias_0,
                                                       nullptr, nullptr, hbuf, nullptr);
    // layer 1 (bf16 hbuf in, + fused classifier)
    edge_kernel<true><<<GB, 512, 0, stream>>>(hbuf, edge_attr, src, dst, ord, rowptr,
                                              prep + PREP_SHORTS, msg);
    agg_kernel<true><<<N_NODES / 4, 256, 0, stream>>>(hbuf, msg, rowptr, root_1, bias_1,
                                                      cls_w, cls_b, nullptr, (float*)d_out);
}

// Round 8
// 94.178 us; speedup vs baseline: 1.6342x; 1.2194x over previous
//
#include <hip/hip_runtime.h>
#include <hip/hip_bf16.h>
#include <math.h>

#define N_NODES 20000
#define N_EDGES 200000
#define D_H 32
#define E_DIM 16
#define CAP 40                          // padded slots per node (max degree bound)
#define NTILES (N_EDGES / 16)           // 12500
#define NJOBS (NTILES / 2)              // 6250 (2 tiles per wave-job)
#define W2S_SHORTS (17 * 2 * 64 * 8)    // 17408 bf16: 17 K-steps x 2 col-tiles x 64 lanes x 8
#define PREP_SHORTS (W2S_SHORTS + 512)  // + w1/b1 A-fragment = 17920

typedef __attribute__((ext_vector_type(8))) short bf16x8;
typedef __attribute__((ext_vector_type(4))) float f32x4;

__device__ __forceinline__ float elu_f(float v) { return v > 0.f ? v : expm1f(v); }
__device__ __forceinline__ short f2bf(float f) {
    union { __hip_bfloat16 h; short s; } u;
    u.h = __float2bfloat16(f);
    return u.s;
}
__device__ __forceinline__ float bf2f(__hip_bfloat16 h) { return __bfloat162float(h); }

// ---------------- init: zero cnt + build bf16 weight fragments (both layers) ----------------
__global__ __launch_bounds__(256)
void init_kernel(const float* __restrict__ w2_0, const float* __restrict__ b2_0,
                 const float* __restrict__ w1_0, const float* __restrict__ b1_0,
                 const float* __restrict__ w2_1, const float* __restrict__ b2_1,
                 const float* __restrict__ w1_1, const float* __restrict__ b1_1,
                 int* __restrict__ cnt, short* __restrict__ prep)
{
    const int gid = blockIdx.x * 256 + threadIdx.x;
    if (gid < N_NODES) cnt[gid] = 0;
    if (gid < 2 * PREP_SHORTS) {
        int layer = gid >= PREP_SHORTS ? 1 : 0;
        int r = gid - layer * PREP_SHORTS;
        const float* w2 = layer ? w2_1 : w2_0;
        const float* b2 = layer ? b2_1 : b2_0;
        const float* w1 = layer ? w1_1 : w1_0;
        const float* b1 = layer ? b1_1 : b1_0;
        float v;
        if (r < W2S_SHORTS) {
            int j = r & 7, l = (r >> 3) & 63, ct = (r >> 9) & 1, kk = r >> 10;
            int ii = (l >> 4) * 8 + j;
            int o = ct * 16 + (l & 15);
            v = (kk < 16) ? w2[kk * 1024 + ii * 32 + o] : b2[ii * 32 + o];
        } else {
            int q = r - W2S_SHORTS;
            int j = q & 7, l = q >> 3;
            int m = l & 15, k = (l >> 4) * 8 + j;
            v = (k < 16) ? w1[k * 16 + m] : (k == 16 ? b1[m] : 0.f);
        }
        prep[gid] = f2bf(v);
    }
}

// ---------------- histogram + arrival rank (CSR fallback path) ----------------
__global__ __launch_bounds__(256)
void hist_kernel(const int* __restrict__ dst, int* __restrict__ cnt, int* __restrict__ ord) {
    int e = blockIdx.x * 256 + threadIdx.x;
    if (e < N_EDGES) ord[e] = atomicAdd(&cnt[dst[e]], 1);
}

// ---------------- exclusive scan of counts -> rowptr (CSR fallback path) ----------------
__global__ __launch_bounds__(1024)
void scan_kernel(const int* __restrict__ cnt, int* __restrict__ rowptr) {
    __shared__ int part[1024];
    const int t = threadIdx.x;
    const int base = t * 20;
    int loc[20];
    int sum = 0;
    #pragma unroll
    for (int j = 0; j < 20; ++j) {
        int idx = base + j;
        int v = (idx < N_NODES) ? cnt[idx] : 0;
        loc[j] = v;
        sum += v;
    }
    part[t] = sum;
    __syncthreads();
    for (int off = 1; off < 1024; off <<= 1) {
        int v = (t >= off) ? part[t - off] : 0;
        __syncthreads();
        part[t] += v;
        __syncthreads();
    }
    int run = part[t] - sum;
    #pragma unroll
    for (int j = 0; j < 20; ++j) {
        int idx = base + j;
        if (idx < N_NODES) { rowptr[idx] = run; run += loc[j]; }
    }
    if (t == 0) rowptr[N_NODES] = N_EDGES;
}

// ---------------- fused edge kernel: 2 tiles (32 edges) per wave ----------------
// MODE 0: padded-first  — ord via inline atomicAdd(cnt), pe = dst*CAP+ord, save pe[e]
// MODE 1: padded-second — pe from saved pe[e]
// MODE 2: CSR           — pe = rowptr[dst]+ord (fallback path)
template<int MODE, bool BF16IN>
__global__ __launch_bounds__(512)
void edge_kernel(const void* __restrict__ xin_,
                 const float* __restrict__ edge_attr,
                 const int* __restrict__ src,
                 const int* __restrict__ dst,
                 int* __restrict__ cnt,          // MODE 0: atomic counters
                 int* __restrict__ pebuf,        // MODE 0: write, MODE 1: read
                 const int* __restrict__ ord,    // MODE 2
                 const int* __restrict__ rowptr, // MODE 2
                 const short* __restrict__ prepL,
                 __hip_bfloat16* __restrict__ msg)
{
    __shared__ __align__(16) short w2s[PREP_SHORTS];   // 35840 B

    const int t = threadIdx.x;
    for (int i = t; i < PREP_SHORTS / 8; i += 512)
        ((int4*)w2s)[i] = ((const int4*)prepL)[i];
    __syncthreads();

    const int lane = t & 63;
    const int wave = t >> 6;
    const int job = blockIdx.x * 8 + wave;
    if (job >= NJOBS) return;
    const int eloc = lane & 15;
    const int kg = lane >> 4;

    const int e0 = job * 32 + eloc;
    const int e1 = e0 + 16;

    // slot addresses
    int pe0, pe1;
    if (MODE == 0) {
        int p0_ = 0, p1_ = 0;
        if (kg == 0) {
            const int d0 = dst[e0], d1 = dst[e1];
            p0_ = d0 * CAP + atomicAdd(&cnt[d0], 1);
            p1_ = d1 * CAP + atomicAdd(&cnt[d1], 1);
            pebuf[e0] = p0_;
            pebuf[e1] = p1_;
        }
        pe0 = __shfl(p0_, eloc);
        pe1 = __shfl(p1_, eloc);
    } else if (MODE == 1) {
        pe0 = pebuf[e0];
        pe1 = pebuf[e1];
    } else {
        pe0 = rowptr[dst[e0]] + ord[e0];
        pe1 = rowptr[dst[e1]] + ord[e1];
    }

    const int sn0 = src[e0], sn1 = src[e1];

    // x B-frags: B[k=kg*8+j][n=eloc] = x[e][kg*8+j]
    bf16x8 xf0, xf1;
    if (BF16IN) {
        const short* xb = (const short*)xin_;
        xf0 = *(const bf16x8*)(xb + (size_t)sn0 * 32 + kg * 8);
        xf1 = *(const bf16x8*)(xb + (size_t)sn1 * 32 + kg * 8);
    } else {
        const float* xf = (const float*)xin_;
        const float4 xa0 = *(const float4*)(xf + (size_t)sn0 * 32 + kg * 8);
        const float4 xa1 = *(const float4*)(xf + (size_t)sn0 * 32 + kg * 8 + 4);
        const float4 xb0 = *(const float4*)(xf + (size_t)sn1 * 32 + kg * 8);
        const float4 xb1 = *(const float4*)(xf + (size_t)sn1 * 32 + kg * 8 + 4);
        xf0[0]=f2bf(xa0.x); xf0[1]=f2bf(xa0.y); xf0[2]=f2bf(xa0.z); xf0[3]=f2bf(xa0.w);
        xf0[4]=f2bf(xa1.x); xf0[5]=f2bf(xa1.y); xf0[6]=f2bf(xa1.z); xf0[7]=f2bf(xa1.w);
        xf1[0]=f2bf(xb0.x); xf1[1]=f2bf(xb0.y); xf1[2]=f2bf(xb0.z); xf1[3]=f2bf(xb0.w);
        xf1[4]=f2bf(xb1.x); xf1[5]=f2bf(xb1.y); xf1[6]=f2bf(xb1.z); xf1[7]=f2bf(xb1.w);
    }

    // edge-attr B-frags: B[k=kg*8+j][n=eloc]; k==16 -> 1.0 (bias), else 0
    bf16x8 ea0 = {0,0,0,0,0,0,0,0}, ea1 = {0,0,0,0,0,0,0,0};
    if (kg < 2) {
        const float4 p0 = *(const float4*)(edge_attr + (size_t)e0 * E_DIM + kg * 8);
        const float4 p1 = *(const float4*)(edge_attr + (size_t)e0 * E_DIM + kg * 8 + 4);
        ea0[0]=f2bf(p0.x); ea0[1]=f2bf(p0.y); ea0[2]=f2bf(p0.z); ea0[3]=f2bf(p0.w);
        ea0[4]=f2bf(p1.x); ea0[5]=f2bf(p1.y); ea0[6]=f2bf(p1.z); ea0[7]=f2bf(p1.w);
        const float4 q0 = *(const float4*)(edge_attr + (size_t)e1 * E_DIM + kg * 8);
        const float4 q1 = *(const float4*)(edge_attr + (size_t)e1 * E_DIM + kg * 8 + 4);
        ea1[0]=f2bf(q0.x); ea1[1]=f2bf(q0.y); ea1[2]=f2bf(q0.z); ea1[3]=f2bf(q0.w);
        ea1[4]=f2bf(q1.x); ea1[5]=f2bf(q1.y); ea1[6]=f2bf(q1.z); ea1[7]=f2bf(q1.w);
    } else if (kg == 2) {
        ea0[0] = f2bf(1.0f);
        ea1[0] = f2bf(1.0f);
    }

    const f32x4 zero4 = {0.f, 0.f, 0.f, 0.f};

    // h-MFMA (swapped): lane holds h[k_out=(lane>>4)*4+r][edge=lane&15]
    bf16x8 w1f = *(const bf16x8*)&w2s[W2S_SHORTS + lane * 8];
    f32x4 hd0 = __builtin_amdgcn_mfma_f32_16x16x32_bf16(w1f, ea0, zero4, 0, 0, 0);
    f32x4 hd1 = __builtin_amdgcn_mfma_f32_16x16x32_bf16(w1f, ea1, zero4, 0, 0, 0);
    float hv0[4], hv1[4];
    #pragma unroll
    for (int r = 0; r < 4; ++r) { hv0[r] = elu_f(hd0[r]); hv1[r] = elu_f(hd1[r]); }

    float m00[4]={0,0,0,0}, m01[4]={0,0,0,0}, m10[4]={0,0,0,0}, m11[4]={0,0,0,0};
    #pragma unroll
    for (int kk = 0; kk < 17; ++kk) {
        bf16x8 a0 = *(const bf16x8*)&w2s[(kk * 2 + 0) * 512 + lane * 8];
        bf16x8 a1 = *(const bf16x8*)&w2s[(kk * 2 + 1) * 512 + lane * 8];
        float h0, h1;
        if (kk < 16) {
            h0 = __shfl(hv0[kk & 3], (kk >> 2) * 16 + eloc);
            h1 = __shfl(hv1[kk & 3], (kk >> 2) * 16 + eloc);
        } else {
            h0 = 1.0f; h1 = 1.0f;   // b2 K-step
        }
        f32x4 d00 = __builtin_amdgcn_mfma_f32_16x16x32_bf16(a0, xf0, zero4, 0, 0, 0);
        f32x4 d01 = __builtin_amdgcn_mfma_f32_16x16x32_bf16(a1, xf0, zero4, 0, 0, 0);
        f32x4 d10 = __builtin_amdgcn_mfma_f32_16x16x32_bf16(a0, xf1, zero4, 0, 0, 0);
        f32x4 d11 = __builtin_amdgcn_mfma_f32_16x16x32_bf16(a1, xf1, zero4, 0, 0, 0);
        #pragma unroll
        for (int r = 0; r < 4; ++r) {
            m00[r] += h0 * d00[r]; m01[r] += h0 * d01[r];
            m10[r] += h1 * d10[r]; m11[r] += h1 * d11[r];
        }
    }

    // stores: lane owns msg[pe][kg*4..+3] and msg[pe][16+kg*4..+3]
    short* mp0 = (short*)(msg + (size_t)pe0 * D_H);
    short* mp1 = (short*)(msg + (size_t)pe1 * D_H);
    short q00[4] = { f2bf(m00[0]), f2bf(m00[1]), f2bf(m00[2]), f2bf(m00[3]) };
    short q01[4] = { f2bf(m01[0]), f2bf(m01[1]), f2bf(m01[2]), f2bf(m01[3]) };
    short q10[4] = { f2bf(m10[0]), f2bf(m10[1]), f2bf(m10[2]), f2bf(m10[3]) };
    short q11[4] = { f2bf(m11[0]), f2bf(m11[1]), f2bf(m11[2]), f2bf(m11[3]) };
    *(int2*)(mp0 + kg * 4)      = *(int2*)q00;
    *(int2*)(mp0 + 16 + kg * 4) = *(int2*)q01;
    *(int2*)(mp1 + kg * 4)      = *(int2*)q10;
    *(int2*)(mp1 + 16 + kg * 4) = *(int2*)q11;
}

// ---------------- aggregation: wave per node + root GEMM + ELU (+ fused classifier) ----------------
// PADDED: rows at n*CAP, count = cnt[n].  else CSR rowptr.
template<bool LAST, bool PADDED>
__global__ __launch_bounds__(256)
void agg_kernel(const void* __restrict__ xin_,
                const __hip_bfloat16* __restrict__ msg,
                const int* __restrict__ rowptr,   // CSR
                const int* __restrict__ cnt,      // PADDED
                const float* __restrict__ root,
                const float* __restrict__ bias,
                const float* __restrict__ cls_w,
                const float* __restrict__ cls_b,
                __hip_bfloat16* __restrict__ hout,
                float* __restrict__ out)
{
    __shared__ float root_s[32 * 32];
    __shared__ float bias_s[32];
    __shared__ float h2_s[4][33];
    const int t = threadIdx.x;
    for (int i = t; i < 1024; i += 256) root_s[i] = root[i];
    if (t < 32) bias_s[t] = bias[t];
    __syncthreads();

    const int lane = t & 63;
    const int wave = t >> 6;
    const int o = lane & 31;
    const int half = lane >> 5;
    const int n = blockIdx.x * 4 + wave;

    int start, end;
    if (PADDED) { start = n * CAP; end = start + cnt[n]; }
    else        { start = rowptr[n]; end = rowptr[n + 1]; }

    float s = 0.f;
    int j = start + half;
    for (; j + 6 < end; j += 8) {   // 4 independent row-loads in flight per half
        float v0 = bf2f(msg[(size_t)(j    ) * D_H + o]);
        float v1 = bf2f(msg[(size_t)(j + 2) * D_H + o]);
        float v2 = bf2f(msg[(size_t)(j + 4) * D_H + o]);
        float v3 = bf2f(msg[(size_t)(j + 6) * D_H + o]);
        s += (v0 + v1) + (v2 + v3);
    }
    for (; j < end; j += 2)
        s += bf2f(msg[(size_t)j * D_H + o]);
    s += __shfl_xor(s, 32);

    float acc = s * (1.f / fmaxf((float)(end - start), 1.f)) + bias_s[o];
    const float xv = LAST ? bf2f(((const __hip_bfloat16*)xin_)[(size_t)n * 32 + o])
                          : ((const float*)xin_)[(size_t)n * 32 + o];
    #pragma unroll
    for (int i = 0; i < 32; ++i)
        acc += __shfl(xv, half * 32 + i) * root_s[i * 32 + o];
    acc = elu_f(acc);

    if (!LAST) {
        if (half == 0) hout[(size_t)n * 32 + o] = __float2bfloat16(acc);
    } else {
        if (half == 0) h2_s[wave][o] = acc;
        __syncthreads();
        if (t < 32) {
            const int nn = t >> 3, jj = t & 7;
            float a = cls_b[jj];
            #pragma unroll
            for (int i = 0; i < 32; ++i) a += h2_s[nn][i] * cls_w[i * 8 + jj];
            out[(size_t)(blockIdx.x * 4 + nn) * 8 + jj] = a;
        }
    }
}

extern "C" void kernel_launch(void* const* d_in, const int* in_sizes, int n_in,
                              void* d_out, int out_size, void* d_ws, size_t ws_size,
                              hipStream_t stream)
{
    const float* x          = (const float*)d_in[0];
    const float* edge_attr  = (const float*)d_in[1];
    const int*   edge_index = (const int*)d_in[2];
    const float* w1_0 = (const float*)d_in[3];
    const float* b1_0 = (const float*)d_in[4];
    const float* w2_0 = (const float*)d_in[5];
    const float* b2_0 = (const float*)d_in[6];
    const float* root_0 = (const float*)d_in[7];
    const float* bias_0 = (const float*)d_in[8];
    const float* w1_1 = (const float*)d_in[9];
    const float* b1_1 = (const float*)d_in[10];
    const float* w2_1 = (const float*)d_in[11];
    const float* b2_1 = (const float*)d_in[12];
    const float* root_1 = (const float*)d_in[13];
    const float* bias_1 = (const float*)d_in[14];
    const float* cls_w = (const float*)d_in[15];
    const float* cls_b = (const float*)d_in[16];

    const int* src = edge_index;
    const int* dst = edge_index + N_EDGES;

    const int EB = (N_EDGES + 255) / 256;         // 782
    const int IB = (2 * PREP_SHORTS + 255) / 256; // 140 (covers N_NODES too)
    const int GB = (NJOBS + 7) / 8;               // 782

    // ---- padded-path workspace layout ----
    size_t need = 0;
    size_t o_cnt = need;  need += (size_t)N_NODES * 4;
    size_t o_pe  = need;  need += (size_t)N_EDGES * 4;
    size_t o_prep= (need + 15) & ~(size_t)15; need = o_prep + (size_t)2 * PREP_SHORTS * 2;
    size_t o_msg = (need + 63) & ~(size_t)63; need = o_msg + (size_t)N_NODES * CAP * D_H * 2;
    size_t o_hb  = (need + 15) & ~(size_t)15; need = o_hb + (size_t)N_NODES * D_H * 2;

    char* ws = (char*)d_ws;

    if (ws_size >= need) {
        // ======== 5-dispatch padded path ========
        int* cnt = (int*)(ws + o_cnt);
        int* pe  = (int*)(ws + o_pe);
        short* prep = (short*)(ws + o_prep);
        __hip_bfloat16* msg  = (__hip_bfloat16*)(ws + o_msg);
        __hip_bfloat16* hbuf = (__hip_bfloat16*)(ws + o_hb);

        init_kernel<<<IB, 256, 0, stream>>>(w2_0, b2_0, w1_0, b1_0,
                                            w2_1, b2_1, w1_1, b1_1, cnt, prep);
        edge_kernel<0, false><<<GB, 512, 0, stream>>>(x, edge_attr, src, dst,
                                                      cnt, pe, nullptr, nullptr, prep, msg);
        agg_kernel<false, true><<<N_NODES / 4, 256, 0, stream>>>(x, msg, nullptr, cnt,
                                                                 root_0, bias_0, nullptr, nullptr,
                                                                 hbuf, nullptr);
        edge_kernel<1, true><<<GB, 512, 0, stream>>>(hbuf, edge_attr, src, dst,
                                                     nullptr, pe, nullptr, nullptr,
                                                     prep + PREP_SHORTS, msg);
        agg_kernel<true, true><<<N_NODES / 4, 256, 0, stream>>>(hbuf, msg, nullptr, cnt,
                                                                root_1, bias_1, cls_w, cls_b,
                                                                nullptr, (float*)d_out);
    } else {
        // ======== 7-dispatch CSR fallback (R7-proven) ========
        int* cnt    = (int*)ws;                            // 20000
        int* rowptr = cnt + N_NODES;                       // 20001
        int* ord    = rowptr + N_NODES + 1;                // 200000
        size_t off = ((size_t)(2 * N_NODES + 1 + N_EDGES) * 4 + 15) & ~(size_t)15;
        short* prep = (short*)(ws + off);
        off = (off + (size_t)2 * PREP_SHORTS * 2 + 15) & ~(size_t)15;
        __hip_bfloat16* msg = (__hip_bfloat16*)(ws + off);
        off = (off + (size_t)N_EDGES * D_H * 2 + 15) & ~(size_t)15;
        __hip_bfloat16* hbuf = (__hip_bfloat16*)(ws + off);

        init_kernel<<<IB, 256, 0, stream>>>(w2_0, b2_0, w1_0, b1_0,
                                            w2_1, b2_1, w1_1, b1_1, cnt, prep);
        hist_kernel<<<EB, 256, 0, stream>>>(dst, cnt, ord);
        scan_kernel<<<1, 1024, 0, stream>>>(cnt, rowptr);

        edge_kernel<2, false><<<GB, 512, 0, stream>>>(x, edge_attr, src, dst,
                                                      nullptr, nullptr, ord, rowptr, prep, msg);
        agg_kernel<false, false><<<N_NODES / 4, 256, 0, stream>>>(x, msg, rowptr, nullptr,
                                                                  root_0, bias_0, nullptr, nullptr,
                                                                  hbuf, nullptr);
        edge_kernel<2, true><<<GB, 512, 0, stream>>>(hbuf, edge_attr, src, dst,
                                                     nullptr, nullptr, ord, rowptr,
                                                     prep + PREP_SHORTS, msg);
        agg_kernel<true, false><<<N_NODES / 4, 256, 0, stream>>>(hbuf, msg, rowptr, nullptr,
                                                                 root_1, bias_1, cls_w, cls_b,
                                                                 nullptr, (float*)d_out);
    }
}